// Round 1
// baseline (2224.152 us; speedup 1.0000x reference)
//
#include <hip/hip_runtime.h>
#include <math.h>

#define BB 4096
#define HH 200
#define DUU 64
#define DVV 64

__device__ __forceinline__ float wave_reduce_sum(float v) {
#pragma unroll
    for (int m = 32; m >= 1; m >>= 1) v += __shfl_xor(v, m, 64);
    return v;
}

__device__ __forceinline__ float wave_reduce_max(float v) {
#pragma unroll
    for (int m = 32; m >= 1; m >>= 1) v = fmaxf(v, __shfl_xor(v, m, 64));
    return v;
}

__global__ __launch_bounds__(256) void uv_agg(
    const int* __restrict__ nodes,
    const int* __restrict__ history_uv,
    const float* __restrict__ history_r,
    const float* __restrict__ u2e_w,
    const float* __restrict__ v2e_w,
    const float* __restrict__ w_r1_w, const float* __restrict__ w_r1_b,
    const float* __restrict__ w_r2_w, const float* __restrict__ w_r2_b,
    const float* __restrict__ att1_w, const float* __restrict__ att1_b,
    const float* __restrict__ att2_w, const float* __restrict__ att2_b,
    const float* __restrict__ att3_w, const float* __restrict__ att3_b,
    float* __restrict__ out)
{
    const int b    = blockIdx.x;
    const int t    = threadIdx.x;
    const int lane = t & 63;
    const int wv   = t >> 6;
    const int h    = (t < HH) ? t : (HH - 1);

    __shared__ float red[4][DVV];
    __shared__ float smax[4];
    __shared__ float ssum[4];

    // ---- gather e_uv (per-thread random row, contiguous 256B -> float4 x16)
    const int   vidx = history_uv[b * HH + h];
    const float r    = history_r[b * HH + h];
    float e[DVV];
    {
        const float4* vrow = reinterpret_cast<const float4*>(v2e_w + (long long)vidx * DVV);
#pragma unroll
        for (int i = 0; i < DVV / 4; ++i) {
            float4 v = vrow[i];
            e[4 * i + 0] = v.x; e[4 * i + 1] = v.y;
            e[4 * i + 2] = v.z; e[4 * i + 3] = v.w;
        }
    }
    // u_rep row: uniform per block -> scalar loads
    const float* urow = u2e_w + (long long)nodes[b] * DUU;

    // ---- layer 1: x1 = relu(W1 * [e, r] + b1), W1 is [64][65]
    float x1[DVV];
#pragma unroll
    for (int o = 0; o < DVV; ++o) {
        const float* w = w_r1_w + o * (DVV + 1);
        float acc = fmaf(w[DVV], r, w_r1_b[o]);
#pragma unroll
        for (int i = 0; i < DVV; ++i) acc = fmaf(w[i], e[i], acc);
        x1[o] = fmaxf(acc, 0.f);
    }

    // ---- layer 2: o_history = relu(W2 * x1 + b2), W2 is [64][64]
    float oh[DVV];
#pragma unroll
    for (int o = 0; o < DVV; ++o) {
        const float* w = w_r2_w + o * DVV;
        float acc = w_r2_b[o];
#pragma unroll
        for (int i = 0; i < DVV; ++i) acc = fmaf(w[i], x1[i], acc);
        oh[o] = fmaxf(acc, 0.f);
    }

    // ---- layer 3: a1 = relu(A1 * [o_history, u_rep] + b), A1 is [64][128]
    float a1[DVV];
#pragma unroll
    for (int o = 0; o < DVV; ++o) {
        const float* w = att1_w + o * (DVV + DUU);
        float acc = att1_b[o];
#pragma unroll
        for (int i = 0; i < DVV; ++i) acc = fmaf(w[i], oh[i], acc);
#pragma unroll
        for (int j = 0; j < DUU; ++j) acc = fmaf(w[DVV + j], urow[j], acc);
        a1[o] = fmaxf(acc, 0.f);
    }

    // ---- layer 4: a2 = relu(A2 * a1 + b), A2 is [64][64]
    float a2[DVV];
#pragma unroll
    for (int o = 0; o < DVV; ++o) {
        const float* w = att2_w + o * DVV;
        float acc = att2_b[o];
#pragma unroll
        for (int i = 0; i < DVV; ++i) acc = fmaf(w[i], a1[i], acc);
        a2[o] = fmaxf(acc, 0.f);
    }

    // ---- layer 5: logit = att3 . a2 + b
    float logit = att3_b[0];
#pragma unroll
    for (int i = 0; i < DVV; ++i) logit = fmaf(att3_w[i], a2[i], logit);
    if (t >= HH) logit = -INFINITY;

    // ---- softmax over h (block-wide, 4 waves)
    float m = wave_reduce_max(logit);
    if (lane == 0) smax[wv] = m;
    __syncthreads();
    m = fmaxf(fmaxf(smax[0], smax[1]), fmaxf(smax[2], smax[3]));

    float ev = (t < HH) ? expf(logit - m) : 0.f;
    float sm = wave_reduce_sum(ev);
    if (lane == 0) ssum[wv] = sm;
    __syncthreads();
    const float total = ssum[0] + ssum[1] + ssum[2] + ssum[3];
    const float att = ev / total;

    // ---- attention-weighted neighbor sum: out[b][d] = sum_h oh[h][d] * att[h]
#pragma unroll
    for (int d = 0; d < DVV; ++d) {
        float v = wave_reduce_sum(oh[d] * att);
        if (lane == 0) red[wv][d] = v;
    }
    __syncthreads();
    if (t < DVV) {
        out[b * DVV + t] = red[0][t] + red[1][t] + red[2][t] + red[3][t];
    }
}

extern "C" void kernel_launch(void* const* d_in, const int* in_sizes, int n_in,
                              void* d_out, int out_size, void* d_ws, size_t ws_size,
                              hipStream_t stream) {
    uv_agg<<<BB, 256, 0, stream>>>(
        (const int*)d_in[0],          // nodes
        (const int*)d_in[1],          // history_uv
        (const float*)d_in[2],        // history_r
        (const float*)d_in[3],        // u2e_w
        (const float*)d_in[4],        // v2e_w
        (const float*)d_in[5],  (const float*)d_in[6],   // w_r1
        (const float*)d_in[7],  (const float*)d_in[8],   // w_r2
        (const float*)d_in[9],  (const float*)d_in[10],  // att1
        (const float*)d_in[11], (const float*)d_in[12],  // att2
        (const float*)d_in[13], (const float*)d_in[14],  // att3
        (float*)d_out);
}

// Round 2
// 209.671 us; speedup vs baseline: 10.6078x; 10.6078x over previous
//
#include <hip/hip_runtime.h>
#include <hip/hip_bf16.h>
#include <math.h>

#define Bn 4096
#define Hn 200

typedef float f32x16 __attribute__((ext_vector_type(16)));
typedef short short8 __attribute__((ext_vector_type(8)));
typedef __bf16 bh8 __attribute__((ext_vector_type(8)));
typedef unsigned int u32;

union Frag { u32 w[4]; short8 s; };

__device__ __forceinline__ u32 pk2(float a, float b){
    union { __hip_bfloat162 bf; u32 u; } cv;
    cv.bf = __float22bfloat162_rn(make_float2(a, b));   // x = low 16 bits = first k
    return cv.u;
}

// builtin signature hedge: prefers direct short8 call; falls back to __bf16 vector.
template <typename T>
__device__ __forceinline__ auto mfma_sel(T a, T b, f32x16 c, int)
    -> decltype(__builtin_amdgcn_mfma_f32_32x32x16_bf16(a, b, c, 0, 0, 0)) {
    return __builtin_amdgcn_mfma_f32_32x32x16_bf16(a, b, c, 0, 0, 0);
}
template <typename T>
__device__ __forceinline__ f32x16 mfma_sel(T a, T b, f32x16 c, long) {
    return __builtin_amdgcn_mfma_f32_32x32x16_bf16(
        __builtin_bit_cast(bh8, a), __builtin_bit_cast(bh8, b), c, 0, 0, 0);
}

__device__ __forceinline__ f32x16 mfma16(const u32* a, const u32* b, f32x16 c){
    Frag fa, fb;
#pragma unroll
    for (int i = 0; i < 4; ++i){ fa.w[i] = a[i]; fb.w[i] = b[i]; }
    return mfma_sel(fa.s, fb.s, c, 0);
}

// D-tile (32x32, col=lane&31, row=(reg&3)+8*(reg>>2)+4*(lane>>5)) -> B-operand
// fragments for the next layer (lane holds col m, k = 8*(lane>>5)+2v+s per chunk).
__device__ __forceinline__ void dtile_to_b(f32x16 d, u32 ow[2][4]){
    u32 p0 = pk2(d[0], d[1]),   p1 = pk2(d[2], d[3]);
    u32 p2 = pk2(d[4], d[5]),   p3 = pk2(d[6], d[7]);
    u32 p4 = pk2(d[8], d[9]),   p5 = pk2(d[10], d[11]);
    u32 p6 = pk2(d[12], d[13]), p7 = pk2(d[14], d[15]);
    auto r0 = __builtin_amdgcn_permlane32_swap(p0, p2, false, false);
    ow[0][0] = (u32)r0[0]; ow[0][2] = (u32)r0[1];
    auto r1 = __builtin_amdgcn_permlane32_swap(p1, p3, false, false);
    ow[0][1] = (u32)r1[0]; ow[0][3] = (u32)r1[1];
    auto r2 = __builtin_amdgcn_permlane32_swap(p4, p6, false, false);
    ow[1][0] = (u32)r2[0]; ow[1][2] = (u32)r2[1];
    auto r3 = __builtin_amdgcn_permlane32_swap(p5, p7, false, false);
    ow[1][1] = (u32)r3[0]; ow[1][3] = (u32)r3[1];
}

__device__ __forceinline__ void load_wfrag2(const float* p, u32 f[4]){  // 8B-aligned rows
    const float2* q = (const float2*)p;
    float2 a = q[0], b = q[1], c = q[2], d = q[3];
    f[0] = pk2(a.x, a.y); f[1] = pk2(b.x, b.y); f[2] = pk2(c.x, c.y); f[3] = pk2(d.x, d.y);
}
__device__ __forceinline__ void load_wfrag1(const float* p, u32 f[4]){  // unaligned (stride 65)
    f[0] = pk2(p[0], p[1]); f[1] = pk2(p[2], p[3]); f[2] = pk2(p[4], p[5]); f[3] = pk2(p[6], p[7]);
}

// generic K=64 layer with ReLU: out = relu(W[64][ldw] * inB + bias), transposed to B-frags
__device__ __forceinline__ void layer64(const float* __restrict__ Wg, int ldw,
                                        const float* __restrict__ bias,
                                        const u32 (&inB)[2][4][4], u32 (&outB)[2][4][4],
                                        int lo, int h)
{
    f32x16 acc[2][2];
#pragma unroll
    for (int ft = 0; ft < 2; ++ft){
        u32 W[4][4];
        const int o = 32 * ft + lo;
#pragma unroll
        for (int kc = 0; kc < 4; ++kc) load_wfrag2(Wg + o * ldw + 16 * kc + 8 * h, W[kc]);
        float bf[16];
#pragma unroll
        for (int rg = 0; rg < 16; ++rg)
            bf[rg] = bias[32 * ft + (rg & 3) + 8 * (rg >> 2) + 4 * h];
#pragma unroll
        for (int rt = 0; rt < 2; ++rt){
            f32x16 a;
#pragma unroll
            for (int rg = 0; rg < 16; ++rg) a[rg] = bf[rg];
#pragma unroll
            for (int kc = 0; kc < 4; ++kc) a = mfma16(W[kc], inB[rt][kc], a);
            acc[ft][rt] = a;
        }
    }
#pragma unroll
    for (int ft = 0; ft < 2; ++ft)
#pragma unroll
        for (int rt = 0; rt < 2; ++rt){
            f32x16 a = acc[ft][rt];
#pragma unroll
            for (int i = 0; i < 16; ++i) a[i] = fmaxf(a[i], 0.f);
            u32 ow[2][4];
            dtile_to_b(a, ow);
#pragma unroll
            for (int v = 0; v < 4; ++v){ outB[rt][2*ft][v] = ow[0][v]; outB[rt][2*ft+1][v] = ow[1][v]; }
        }
}

__global__ __launch_bounds__(256, 2) void uv_agg(
    const int* __restrict__ nodes,
    const int* __restrict__ history_uv,
    const float* __restrict__ history_r,
    const float* __restrict__ u2e_w,
    const float* __restrict__ v2e_w,
    const float* __restrict__ w_r1_w, const float* __restrict__ w_r1_b,
    const float* __restrict__ w_r2_w, const float* __restrict__ w_r2_b,
    const float* __restrict__ att1_w, const float* __restrict__ att1_b,
    const float* __restrict__ att2_w, const float* __restrict__ att2_b,
    const float* __restrict__ att3_w, const float* __restrict__ att3_b,
    float* __restrict__ out)
{
    const int b  = blockIdx.x;
    const int t  = threadIdx.x;
    const int w  = t >> 6;
    const int l  = t & 63;
    const int lo = l & 31;
    const int h  = l >> 5;

    __shared__ u32   oh_lds[256 * 32];   // 32 KiB, word col c=feat/2 stored at (c ^ (m&31))
    __shared__ float att_lds[256];
    __shared__ float red[4][64];
    __shared__ float swax[4], ssum[4];

    // ---- gather indices (clamped for pad rows; masked later)
    const int hb  = b * Hn;
    const int m0  = 64 * w + lo;
    const int m1  = m0 + 32;
    const int mi0 = m0 < Hn ? m0 : Hn - 1;
    const int mi1 = m1 < Hn ? m1 : Hn - 1;
    const int vidx0 = history_uv[hb + mi0];
    const int vidx1 = history_uv[hb + mi1];
    const float r0  = history_r[hb + mi0];
    const float r1  = history_r[hb + mi1];

    // ---- e_uv B-fragments (lane = col m, 8 contiguous k per lane-half)
    u32 eB[2][4][4];
    {
        const float4* p0 = (const float4*)(v2e_w + vidx0 * 64);
        const float4* p1 = (const float4*)(v2e_w + vidx1 * 64);
#pragma unroll
        for (int kc = 0; kc < 4; ++kc){
            float4 a = p0[4*kc + 2*h], c = p0[4*kc + 2*h + 1];
            eB[0][kc][0] = pk2(a.x, a.y); eB[0][kc][1] = pk2(a.z, a.w);
            eB[0][kc][2] = pk2(c.x, c.y); eB[0][kc][3] = pk2(c.z, c.w);
            a = p1[4*kc + 2*h]; c = p1[4*kc + 2*h + 1];
            eB[1][kc][0] = pk2(a.x, a.y); eB[1][kc][1] = pk2(a.z, a.w);
            eB[1][kc][2] = pk2(c.x, c.y); eB[1][kc][3] = pk2(c.z, c.w);
        }
    }
    // ---- u_rep B-fragments (broadcast across cols)
    u32 uB[4][4];
    {
        const int node = nodes[b];
        const float4* p = (const float4*)(u2e_w + node * 64);
#pragma unroll
        for (int kc = 0; kc < 4; ++kc){
            float4 a = p[4*kc + 2*h], c = p[4*kc + 2*h + 1];
            uB[kc][0] = pk2(a.x, a.y); uB[kc][1] = pk2(a.z, a.w);
            uB[kc][2] = pk2(c.x, c.y); uB[kc][3] = pk2(c.z, c.w);
        }
    }

    // ---- layer 1: x1 = relu(W1[:, :64] @ e + w1r * r + b1)   (r folded into C-in)
    u32 x1B[2][4][4];
    {
        f32x16 acc[2][2];
#pragma unroll
        for (int ft = 0; ft < 2; ++ft){
            u32 W[4][4];
            const int o = 32 * ft + lo;
#pragma unroll
            for (int kc = 0; kc < 4; ++kc) load_wfrag1(w_r1_w + o * 65 + 16 * kc + 8 * h, W[kc]);
            float bf[16], wr[16];
#pragma unroll
            for (int rg = 0; rg < 16; ++rg){
                int orow = 32 * ft + (rg & 3) + 8 * (rg >> 2) + 4 * h;
                bf[rg] = w_r1_b[orow];
                wr[rg] = w_r1_w[orow * 65 + 64];
            }
#pragma unroll
            for (int rt = 0; rt < 2; ++rt){
                const float rv = rt ? r1 : r0;
                f32x16 a;
#pragma unroll
                for (int rg = 0; rg < 16; ++rg) a[rg] = fmaf(wr[rg], rv, bf[rg]);
#pragma unroll
                for (int kc = 0; kc < 4; ++kc) a = mfma16(W[kc], eB[rt][kc], a);
                acc[ft][rt] = a;
            }
        }
#pragma unroll
        for (int ft = 0; ft < 2; ++ft)
#pragma unroll
            for (int rt = 0; rt < 2; ++rt){
                f32x16 a = acc[ft][rt];
#pragma unroll
                for (int i = 0; i < 16; ++i) a[i] = fmaxf(a[i], 0.f);
                u32 ow[2][4];
                dtile_to_b(a, ow);
#pragma unroll
                for (int v = 0; v < 4; ++v){ x1B[rt][2*ft][v] = ow[0][v]; x1B[rt][2*ft+1][v] = ow[1][v]; }
            }
    }

    // ---- layer 2: o_history = relu(W2 @ x1 + b2)
    u32 ohB[2][4][4];
    layer64(w_r2_w, 64, w_r2_b, x1B, ohB, lo, h);

    // stash o_history to LDS (swizzled) for the final weighted sum
#pragma unroll
    for (int kc = 0; kc < 4; ++kc)
#pragma unroll
        for (int rt = 0; rt < 2; ++rt)
#pragma unroll
            for (int v = 0; v < 4; ++v){
                const int c = 8 * kc + 4 * h + v;          // word col = feat/2
                const int m = 64 * w + 32 * rt + lo;
                oh_lds[m * 32 + (c ^ lo)] = ohB[rt][kc][v];
            }

    // ---- layer 3: a1 = relu(A1 @ [o_history ; u_rep] + b)   K=128
    u32 a1B[2][4][4];
    {
        f32x16 acc[2][2];
#pragma unroll
        for (int ft = 0; ft < 2; ++ft){
            const int o = 32 * ft + lo;
            float bf[16];
#pragma unroll
            for (int rg = 0; rg < 16; ++rg)
                bf[rg] = att1_b[32 * ft + (rg & 3) + 8 * (rg >> 2) + 4 * h];
            f32x16 a[2];
#pragma unroll
            for (int rt = 0; rt < 2; ++rt){
#pragma unroll
                for (int rg = 0; rg < 16; ++rg) a[rt][rg] = bf[rg];
            }
            u32 W[4][4];
#pragma unroll
            for (int kc = 0; kc < 4; ++kc) load_wfrag2(att1_w + o * 128 + 16 * kc + 8 * h, W[kc]);
#pragma unroll
            for (int rt = 0; rt < 2; ++rt)
#pragma unroll
                for (int kc = 0; kc < 4; ++kc) a[rt] = mfma16(W[kc], ohB[rt][kc], a[rt]);
            u32 W2[4][4];
#pragma unroll
            for (int kc = 0; kc < 4; ++kc) load_wfrag2(att1_w + o * 128 + 64 + 16 * kc + 8 * h, W2[kc]);
#pragma unroll
            for (int rt = 0; rt < 2; ++rt)
#pragma unroll
                for (int kc = 0; kc < 4; ++kc) a[rt] = mfma16(W2[kc], uB[kc], a[rt]);
            acc[ft][0] = a[0]; acc[ft][1] = a[1];
        }
#pragma unroll
        for (int ft = 0; ft < 2; ++ft)
#pragma unroll
            for (int rt = 0; rt < 2; ++rt){
                f32x16 a = acc[ft][rt];
#pragma unroll
                for (int i = 0; i < 16; ++i) a[i] = fmaxf(a[i], 0.f);
                u32 ow[2][4];
                dtile_to_b(a, ow);
#pragma unroll
                for (int v = 0; v < 4; ++v){ a1B[rt][2*ft][v] = ow[0][v]; a1B[rt][2*ft+1][v] = ow[1][v]; }
            }
    }

    // ---- layer 4: a2 = relu(A2 @ a1 + b)  (keep D-form, no transpose)
    f32x16 acc4[2][2];
    {
#pragma unroll
        for (int ft = 0; ft < 2; ++ft){
            u32 W[4][4];
            const int o = 32 * ft + lo;
#pragma unroll
            for (int kc = 0; kc < 4; ++kc) load_wfrag2(att2_w + o * 64 + 16 * kc + 8 * h, W[kc]);
            float bf[16];
#pragma unroll
            for (int rg = 0; rg < 16; ++rg)
                bf[rg] = att2_b[32 * ft + (rg & 3) + 8 * (rg >> 2) + 4 * h];
#pragma unroll
            for (int rt = 0; rt < 2; ++rt){
                f32x16 a;
#pragma unroll
                for (int rg = 0; rg < 16; ++rg) a[rg] = bf[rg];
#pragma unroll
                for (int kc = 0; kc < 4; ++kc) a = mfma16(W[kc], a1B[rt][kc], a);
#pragma unroll
                for (int i = 0; i < 16; ++i) a[i] = fmaxf(a[i], 0.f);
                acc4[ft][rt] = a;
            }
        }
    }

    // ---- layer 5: logits  (f32 dot across regs + cross-half add)
    float at3[2][16];
#pragma unroll
    for (int ft = 0; ft < 2; ++ft)
#pragma unroll
        for (int rg = 0; rg < 16; ++rg)
            at3[ft][rg] = att3_w[32 * ft + (rg & 3) + 8 * (rg >> 2) + 4 * h];
    const float b3 = att3_b[0];
    float lg[2];
#pragma unroll
    for (int rt = 0; rt < 2; ++rt){
        float p = 0.f;
#pragma unroll
        for (int ft = 0; ft < 2; ++ft)
#pragma unroll
            for (int rg = 0; rg < 16; ++rg) p = fmaf(acc4[ft][rt][rg], at3[ft][rg], p);
        p += __shfl_xor(p, 32, 64);
        lg[rt] = p + b3;
    }
    if (m0 >= Hn) lg[0] = -1e30f;
    if (m1 >= Hn) lg[1] = -1e30f;

    // ---- softmax over the 200 rows (block-wide)
    float mx = fmaxf(lg[0], lg[1]);
#pragma unroll
    for (int d = 16; d >= 1; d >>= 1) mx = fmaxf(mx, __shfl_xor(mx, d, 64));
    if (l == 0) swax[w] = mx;
    __syncthreads();
    mx = fmaxf(fmaxf(swax[0], swax[1]), fmaxf(swax[2], swax[3]));
    const float e0 = exp2f((lg[0] - mx) * 1.4426950408889634f);
    const float e1 = exp2f((lg[1] - mx) * 1.4426950408889634f);
    float sm = e0 + e1;
#pragma unroll
    for (int d = 16; d >= 1; d >>= 1) sm += __shfl_xor(sm, d, 64);
    if (l == 0) ssum[w] = sm;
    __syncthreads();
    const float inv = 1.f / (ssum[0] + ssum[1] + ssum[2] + ssum[3]);
    att_lds[64 * w + 32 * h + lo] = (h ? e1 : e0) * inv;
    __syncthreads();

    // ---- weighted sum: out[dv] = sum_m att[m] * oh[m][dv]
    float s0 = 0.f, s1 = 0.f;
#pragma unroll 8
    for (int i = 0; i < 32; ++i){
        const int m = 64 * w + 32 * h + i;
        const u32 wv = oh_lds[m * 32 + (lo ^ i)];
        const float av = att_lds[m];
        s0 = fmaf(__uint_as_float(wv << 16), av, s0);
        s1 = fmaf(__uint_as_float(wv & 0xffff0000u), av, s1);
    }
    s0 += __shfl_xor(s0, 32, 64);
    s1 += __shfl_xor(s1, 32, 64);
    if (l < 32){ red[w][2 * lo] = s0; red[w][2 * lo + 1] = s1; }
    __syncthreads();
    if (t < 64) out[b * 64 + t] = red[0][t] + red[1][t] + red[2][t] + red[3][t];
}

extern "C" void kernel_launch(void* const* d_in, const int* in_sizes, int n_in,
                              void* d_out, int out_size, void* d_ws, size_t ws_size,
                              hipStream_t stream) {
    uv_agg<<<Bn, 256, 0, stream>>>(
        (const int*)d_in[0],
        (const int*)d_in[1],
        (const float*)d_in[2],
        (const float*)d_in[3],
        (const float*)d_in[4],
        (const float*)d_in[5],  (const float*)d_in[6],
        (const float*)d_in[7],  (const float*)d_in[8],
        (const float*)d_in[9],  (const float*)d_in[10],
        (const float*)d_in[11], (const float*)d_in[12],
        (const float*)d_in[13], (const float*)d_in[14],
        (float*)d_out);
}

// Round 3
// 173.821 us; speedup vs baseline: 12.7957x; 1.2062x over previous
//
#include <hip/hip_runtime.h>
#include <hip/hip_bf16.h>
#include <math.h>

#define Bn 4096
#define Hn 200

typedef float f32x16 __attribute__((ext_vector_type(16)));
typedef short short8 __attribute__((ext_vector_type(8)));
typedef __bf16 bh8 __attribute__((ext_vector_type(8)));
typedef unsigned int u32;

// ---- d_ws layout (u32 units) ----
// [0, TABW)            : bf16 v2e table (100000 rows x 64 feats, 32 words/row)  [optional]
// [woff + c*256 .. )   : 40 weight chunks, chunk c = 64 lanes x uint4
// [woff + BIAS_OFF ..) : f32 bias frags  [layer(4)][ft(2)][h(2)][16]
// [woff + WR_OFF ..)   : f32 w_r1 r-col  [ft][h][16]
// [woff + AT3_OFF ..)  : f32 att3_w      [ft][h][16]
#define TABW     3200000
#define BIAS_OFF 10240
#define WR_OFF   10496
#define AT3_OFF  10560
#define WTOT     10624

union Frag { u32 w[4]; short8 s; };

__device__ __forceinline__ u32 pk2(float a, float b){
    union { __hip_bfloat162 bf; u32 u; } cv;
    cv.bf = __float22bfloat162_rn(make_float2(a, b));   // low 16 bits = first k
    return cv.u;
}

template <typename T>
__device__ __forceinline__ auto mfma_sel(T a, T b, f32x16 c, int)
    -> decltype(__builtin_amdgcn_mfma_f32_32x32x16_bf16(a, b, c, 0, 0, 0)) {
    return __builtin_amdgcn_mfma_f32_32x32x16_bf16(a, b, c, 0, 0, 0);
}
template <typename T>
__device__ __forceinline__ f32x16 mfma_sel(T a, T b, f32x16 c, long) {
    return __builtin_amdgcn_mfma_f32_32x32x16_bf16(
        __builtin_bit_cast(bh8, a), __builtin_bit_cast(bh8, b), c, 0, 0, 0);
}

__device__ __forceinline__ f32x16 mfma16(const u32* a, const u32* b, f32x16 c){
    Frag fa, fb;
#pragma unroll
    for (int i = 0; i < 4; ++i){ fa.w[i] = a[i]; fb.w[i] = b[i]; }
    return mfma_sel(fa.s, fb.s, c, 0);
}
__device__ __forceinline__ f32x16 mfma16v(uint4 a, const u32* b, f32x16 c){
    Frag fa, fb;
    fa.w[0] = a.x; fa.w[1] = a.y; fa.w[2] = a.z; fa.w[3] = a.w;
#pragma unroll
    for (int i = 0; i < 4; ++i) fb.w[i] = b[i];
    return mfma_sel(fa.s, fb.s, c, 0);
}

// D-tile (32x32, col=lane&31, row=(reg&3)+8*(reg>>2)+4*(lane>>5)) -> next-layer B frags
__device__ __forceinline__ void dtile_to_b(f32x16 d, u32 ow[2][4]){
    u32 p0 = pk2(d[0], d[1]),   p1 = pk2(d[2], d[3]);
    u32 p2 = pk2(d[4], d[5]),   p3 = pk2(d[6], d[7]);
    u32 p4 = pk2(d[8], d[9]),   p5 = pk2(d[10], d[11]);
    u32 p6 = pk2(d[12], d[13]), p7 = pk2(d[14], d[15]);
    auto r0 = __builtin_amdgcn_permlane32_swap(p0, p2, false, false);
    ow[0][0] = (u32)r0[0]; ow[0][2] = (u32)r0[1];
    auto r1 = __builtin_amdgcn_permlane32_swap(p1, p3, false, false);
    ow[0][1] = (u32)r1[0]; ow[0][3] = (u32)r1[1];
    auto r2 = __builtin_amdgcn_permlane32_swap(p4, p6, false, false);
    ow[1][0] = (u32)r2[0]; ow[1][2] = (u32)r2[1];
    auto r3 = __builtin_amdgcn_permlane32_swap(p5, p7, false, false);
    ow[1][1] = (u32)r3[0]; ow[1][3] = (u32)r3[1];
}

__device__ __forceinline__ void load_f16(const float* p, float bf[16]){
    const float4* q = (const float4*)p;
    float4 a = q[0], b = q[1], c = q[2], d = q[3];
    bf[0]=a.x; bf[1]=a.y; bf[2]=a.z; bf[3]=a.w;
    bf[4]=b.x; bf[5]=b.y; bf[6]=b.z; bf[7]=b.w;
    bf[8]=c.x; bf[9]=c.y; bf[10]=c.z; bf[11]=c.w;
    bf[12]=d.x; bf[13]=d.y; bf[14]=d.z; bf[15]=d.w;
}

// ======================= prep: pack weights (+ bf16 table) =======================
__global__ __launch_bounds__(256) void prep(
    const float* __restrict__ v2e_w,
    const float* __restrict__ w_r1_w, const float* __restrict__ w_r1_b,
    const float* __restrict__ w_r2_w, const float* __restrict__ w_r2_b,
    const float* __restrict__ att1_w, const float* __restrict__ att1_b,
    const float* __restrict__ att2_w, const float* __restrict__ att2_b,
    const float* __restrict__ att3_w,
    u32* __restrict__ ws, int table_n, int woff)
{
    const int g = blockIdx.x * 256 + threadIdx.x;
    if (g < table_n) {                       // bf16 v2e table: 8 floats -> 1 uint4
        const float4* src = (const float4*)v2e_w + (size_t)g * 2;
        float4 a = src[0], b = src[1];
        uint4 o; o.x = pk2(a.x, a.y); o.y = pk2(a.z, a.w);
                 o.z = pk2(b.x, b.y); o.w = pk2(b.z, b.w);
        ((uint4*)ws)[g] = o;
        return;
    }
    int q = g - table_n;
    u32* wbase = ws + woff;
    if (q < 2560) {                          // weight fragment chunks
        const int c = q >> 6, l = q & 63, lo = l & 31, h = l >> 5;
        const float* W; int ldw, ft, kc, colb;
        if (c < 8)       { W = w_r1_w; ldw = 65;  ft = c >> 2;       kc = c & 3;       colb = 0; }
        else if (c < 16) { W = w_r2_w; ldw = 64;  ft = (c - 8) >> 2; kc = (c - 8) & 3; colb = 0; }
        else if (c < 32) { int c3 = c - 16; W = att1_w; ldw = 128; ft = c3 >> 3; kc = c3 & 3; colb = 64 * ((c3 >> 2) & 1); }
        else             { int c4 = c - 32; W = att2_w; ldw = 64;  ft = c4 >> 2; kc = c4 & 3; colb = 0; }
        const float* p = W + (32 * ft + lo) * ldw + colb + 16 * kc + 8 * h;
        uint4 o; o.x = pk2(p[0], p[1]); o.y = pk2(p[2], p[3]);
                 o.z = pk2(p[4], p[5]); o.w = pk2(p[6], p[7]);
        ((uint4*)wbase)[c * 64 + l] = o;
        return;
    }
    q -= 2560;
    if (q < 256) {                           // biases in acc-reg order
        const int layer = q >> 6, ft = (q >> 5) & 1, h = (q >> 4) & 1, rg = q & 15;
        const float* bp = layer == 0 ? w_r1_b : layer == 1 ? w_r2_b : layer == 2 ? att1_b : att2_b;
        ((float*)wbase)[BIAS_OFF + q] = bp[32 * ft + (rg & 3) + 8 * (rg >> 2) + 4 * h];
        return;
    }
    q -= 256;
    if (q < 64) {                            // w_r1 r-column
        const int ft = (q >> 5) & 1, h = (q >> 4) & 1, rg = q & 15;
        ((float*)wbase)[WR_OFF + q] = w_r1_w[(32 * ft + (rg & 3) + 8 * (rg >> 2) + 4 * h) * 65 + 64];
        return;
    }
    q -= 64;
    if (q < 64) {                            // att3_w
        const int ft = (q >> 5) & 1, h = (q >> 4) & 1, rg = q & 15;
        ((float*)wbase)[AT3_OFF + q] = att3_w[32 * ft + (rg & 3) + 8 * (rg >> 2) + 4 * h];
    }
}

// ======================= main =======================
__global__ __launch_bounds__(256, 4) void uv_agg(
    const int* __restrict__ nodes,
    const int* __restrict__ history_uv,
    const float* __restrict__ history_r,
    const float* __restrict__ u2e_w,
    const float* __restrict__ v2e_w,
    const float* __restrict__ att3_b,
    const u32* __restrict__ ws, int woff, int use_tab,
    float* __restrict__ out)
{
    const int b  = blockIdx.x;
    const int t  = threadIdx.x;
    const int w  = t >> 6;
    const int l  = t & 63;
    const int lo = l & 31;
    const int h  = l >> 5;

    const uint4* WF = (const uint4*)(ws + woff);
    const float* F  = (const float*)(ws + woff);

    __shared__ u32   oh_lds[256 * 32];   // bf16x2 words, col c stored at (c ^ (m&31))
    __shared__ float att_lds[256];
    __shared__ float red[4][64];
    __shared__ float swax[4], ssum[4];

    // ---- gather indices
    const int hb  = b * Hn;
    const int m0  = 64 * w + lo;
    const int m1  = m0 + 32;
    const int mi0 = m0 < Hn ? m0 : Hn - 1;
    const int mi1 = m1 < Hn ? m1 : Hn - 1;
    const int vidx0 = history_uv[hb + mi0];
    const int vidx1 = history_uv[hb + mi1];
    const float r0  = history_r[hb + mi0];
    const float r1  = history_r[hb + mi1];

    // ---- e_uv B-fragments
    u32 eB[2][4][4];
    if (use_tab) {
        const uint4* t0 = (const uint4*)ws + (size_t)vidx0 * 8;
        const uint4* t1 = (const uint4*)ws + (size_t)vidx1 * 8;
#pragma unroll
        for (int kc = 0; kc < 4; ++kc){
            uint4 x = t0[2 * kc + h];
            eB[0][kc][0] = x.x; eB[0][kc][1] = x.y; eB[0][kc][2] = x.z; eB[0][kc][3] = x.w;
            uint4 y = t1[2 * kc + h];
            eB[1][kc][0] = y.x; eB[1][kc][1] = y.y; eB[1][kc][2] = y.z; eB[1][kc][3] = y.w;
        }
    } else {
        const float4* p0 = (const float4*)(v2e_w + (size_t)vidx0 * 64);
        const float4* p1 = (const float4*)(v2e_w + (size_t)vidx1 * 64);
#pragma unroll
        for (int kc = 0; kc < 4; ++kc){
            float4 a = p0[4*kc + 2*h], c = p0[4*kc + 2*h + 1];
            eB[0][kc][0] = pk2(a.x, a.y); eB[0][kc][1] = pk2(a.z, a.w);
            eB[0][kc][2] = pk2(c.x, c.y); eB[0][kc][3] = pk2(c.z, c.w);
            a = p1[4*kc + 2*h]; c = p1[4*kc + 2*h + 1];
            eB[1][kc][0] = pk2(a.x, a.y); eB[1][kc][1] = pk2(a.z, a.w);
            eB[1][kc][2] = pk2(c.x, c.y); eB[1][kc][3] = pk2(c.z, c.w);
        }
    }

    // ---- u_rep B-fragments
    u32 uB[4][4];
    {
        const float4* p = (const float4*)(u2e_w + (size_t)nodes[b] * 64);
#pragma unroll
        for (int kc = 0; kc < 4; ++kc){
            float4 a = p[4*kc + 2*h], c = p[4*kc + 2*h + 1];
            uB[kc][0] = pk2(a.x, a.y); uB[kc][1] = pk2(a.z, a.w);
            uB[kc][2] = pk2(c.x, c.y); uB[kc][3] = pk2(c.z, c.w);
        }
    }

    // ---- layer 1: x1 = relu(W1[:,:64] @ e + w1r*r + b1)
    u32 x1B[2][4][4];
    {
        f32x16 acc[2][2];
#pragma unroll
        for (int ft = 0; ft < 2; ++ft){
            uint4 W[4];
#pragma unroll
            for (int kc = 0; kc < 4; ++kc) W[kc] = WF[(ft*4 + kc)*64 + l];
            float bf[16], wr[16];
            load_f16(F + BIAS_OFF + ft*32 + h*16, bf);
            load_f16(F + WR_OFF + ft*32 + h*16, wr);
#pragma unroll
            for (int rt = 0; rt < 2; ++rt){
                const float rv = rt ? r1 : r0;
                f32x16 a;
#pragma unroll
                for (int rg = 0; rg < 16; ++rg) a[rg] = fmaf(wr[rg], rv, bf[rg]);
#pragma unroll
                for (int kc = 0; kc < 4; ++kc) a = mfma16v(W[kc], eB[rt][kc], a);
                acc[ft][rt] = a;
            }
        }
#pragma unroll
        for (int ft = 0; ft < 2; ++ft)
#pragma unroll
            for (int rt = 0; rt < 2; ++rt){
                f32x16 a = acc[ft][rt];
#pragma unroll
                for (int i = 0; i < 16; ++i) a[i] = fmaxf(a[i], 0.f);
                u32 ow[2][4];
                dtile_to_b(a, ow);
#pragma unroll
                for (int v = 0; v < 4; ++v){ x1B[rt][2*ft][v] = ow[0][v]; x1B[rt][2*ft+1][v] = ow[1][v]; }
            }
    }

    // ---- layer 2: o_history = relu(W2 @ x1 + b2)
    u32 ohB[2][4][4];
    {
        f32x16 acc[2][2];
#pragma unroll
        for (int ft = 0; ft < 2; ++ft){
            uint4 W[4];
#pragma unroll
            for (int kc = 0; kc < 4; ++kc) W[kc] = WF[(8 + ft*4 + kc)*64 + l];
            float bf[16];
            load_f16(F + BIAS_OFF + 64 + ft*32 + h*16, bf);
#pragma unroll
            for (int rt = 0; rt < 2; ++rt){
                f32x16 a;
#pragma unroll
                for (int rg = 0; rg < 16; ++rg) a[rg] = bf[rg];
#pragma unroll
                for (int kc = 0; kc < 4; ++kc) a = mfma16v(W[kc], x1B[rt][kc], a);
                acc[ft][rt] = a;
            }
        }
#pragma unroll
        for (int ft = 0; ft < 2; ++ft)
#pragma unroll
            for (int rt = 0; rt < 2; ++rt){
                f32x16 a = acc[ft][rt];
#pragma unroll
                for (int i = 0; i < 16; ++i) a[i] = fmaxf(a[i], 0.f);
                u32 ow[2][4];
                dtile_to_b(a, ow);
#pragma unroll
                for (int v = 0; v < 4; ++v){ ohB[rt][2*ft][v] = ow[0][v]; ohB[rt][2*ft+1][v] = ow[1][v]; }
            }
    }

    // stash o_history to LDS (swizzled)
#pragma unroll
    for (int kc = 0; kc < 4; ++kc)
#pragma unroll
        for (int rt = 0; rt < 2; ++rt)
#pragma unroll
            for (int v = 0; v < 4; ++v){
                const int c = 8 * kc + 4 * h + v;
                const int m = 64 * w + 32 * rt + lo;
                oh_lds[m * 32 + (c ^ lo)] = ohB[rt][kc][v];
            }

    // ---- layer 3: a1 = relu(A1 @ [oh ; u] + b)   K=128
    u32 a1B[2][4][4];
    {
        f32x16 acc[2][2];
#pragma unroll
        for (int ft = 0; ft < 2; ++ft){
            float bf[16];
            load_f16(F + BIAS_OFF + 128 + ft*32 + h*16, bf);
            f32x16 a[2];
#pragma unroll
            for (int rt = 0; rt < 2; ++rt)
#pragma unroll
                for (int rg = 0; rg < 16; ++rg) a[rt][rg] = bf[rg];
            uint4 W[4];
#pragma unroll
            for (int kc = 0; kc < 4; ++kc) W[kc] = WF[(16 + ft*8 + kc)*64 + l];
#pragma unroll
            for (int rt = 0; rt < 2; ++rt)
#pragma unroll
                for (int kc = 0; kc < 4; ++kc) a[rt] = mfma16v(W[kc], ohB[rt][kc], a[rt]);
            uint4 W2[4];
#pragma unroll
            for (int kc = 0; kc < 4; ++kc) W2[kc] = WF[(16 + ft*8 + 4 + kc)*64 + l];
#pragma unroll
            for (int rt = 0; rt < 2; ++rt)
#pragma unroll
                for (int kc = 0; kc < 4; ++kc) a[rt] = mfma16v(W2[kc], uB[kc], a[rt]);
            acc[ft][0] = a[0]; acc[ft][1] = a[1];
        }
#pragma unroll
        for (int ft = 0; ft < 2; ++ft)
#pragma unroll
            for (int rt = 0; rt < 2; ++rt){
                f32x16 a = acc[ft][rt];
#pragma unroll
                for (int i = 0; i < 16; ++i) a[i] = fmaxf(a[i], 0.f);
                u32 ow[2][4];
                dtile_to_b(a, ow);
#pragma unroll
                for (int v = 0; v < 4; ++v){ a1B[rt][2*ft][v] = ow[0][v]; a1B[rt][2*ft+1][v] = ow[1][v]; }
            }
    }

    // ---- layer 4: a2 = relu(A2 @ a1 + b)   (keep D-form)
    f32x16 acc4[2][2];
#pragma unroll
    for (int ft = 0; ft < 2; ++ft){
        uint4 W[4];
#pragma unroll
        for (int kc = 0; kc < 4; ++kc) W[kc] = WF[(32 + ft*4 + kc)*64 + l];
        float bf[16];
        load_f16(F + BIAS_OFF + 192 + ft*32 + h*16, bf);
#pragma unroll
        for (int rt = 0; rt < 2; ++rt){
            f32x16 a;
#pragma unroll
            for (int rg = 0; rg < 16; ++rg) a[rg] = bf[rg];
#pragma unroll
            for (int kc = 0; kc < 4; ++kc) a = mfma16v(W[kc], a1B[rt][kc], a);
#pragma unroll
            for (int i = 0; i < 16; ++i) a[i] = fmaxf(a[i], 0.f);
            acc4[ft][rt] = a;
        }
    }

    // ---- layer 5: logits
    float at3[2][16];
    load_f16(F + AT3_OFF + h*16, at3[0]);
    load_f16(F + AT3_OFF + 32 + h*16, at3[1]);
    const float b3 = att3_b[0];
    float lg[2];
#pragma unroll
    for (int rt = 0; rt < 2; ++rt){
        float p = 0.f;
#pragma unroll
        for (int ft = 0; ft < 2; ++ft)
#pragma unroll
            for (int rg = 0; rg < 16; ++rg) p = fmaf(acc4[ft][rt][rg], at3[ft][rg], p);
        p += __shfl_xor(p, 32, 64);
        lg[rt] = p + b3;
    }
    if (m0 >= Hn) lg[0] = -1e30f;
    if (m1 >= Hn) lg[1] = -1e30f;

    // ---- softmax over 200 rows
    float mx = fmaxf(lg[0], lg[1]);
#pragma unroll
    for (int d = 16; d >= 1; d >>= 1) mx = fmaxf(mx, __shfl_xor(mx, d, 64));
    if (l == 0) swax[w] = mx;
    __syncthreads();
    mx = fmaxf(fmaxf(swax[0], swax[1]), fmaxf(swax[2], swax[3]));
    const float e0 = exp2f((lg[0] - mx) * 1.4426950408889634f);
    const float e1 = exp2f((lg[1] - mx) * 1.4426950408889634f);
    float sm = e0 + e1;
#pragma unroll
    for (int d = 16; d >= 1; d >>= 1) sm += __shfl_xor(sm, d, 64);
    if (l == 0) ssum[w] = sm;
    __syncthreads();
    const float inv = 1.f / (ssum[0] + ssum[1] + ssum[2] + ssum[3]);
    att_lds[64 * w + 32 * h + lo] = (h ? e1 : e0) * inv;
    __syncthreads();

    // ---- weighted sum: out[d] = sum_m att[m] * oh[m][d]
    float s0 = 0.f, s1 = 0.f;
#pragma unroll 8
    for (int i = 0; i < 32; ++i){
        const int m = 64 * w + 32 * h + i;
        const u32 wv = oh_lds[m * 32 + (lo ^ i)];
        const float av = att_lds[m];
        s0 = fmaf(__uint_as_float(wv << 16), av, s0);
        s1 = fmaf(__uint_as_float(wv & 0xffff0000u), av, s1);
    }
    s0 += __shfl_xor(s0, 32, 64);
    s1 += __shfl_xor(s1, 32, 64);
    if (l < 32){ red[w][2 * lo] = s0; red[w][2 * lo + 1] = s1; }
    __syncthreads();
    if (t < 64) out[b * 64 + t] = red[0][t] + red[1][t] + red[2][t] + red[3][t];
}

extern "C" void kernel_launch(void* const* d_in, const int* in_sizes, int n_in,
                              void* d_out, int out_size, void* d_ws, size_t ws_size,
                              hipStream_t stream) {
    u32* ws = (u32*)d_ws;
    const size_t need_tab = (size_t)(TABW + WTOT) * 4;
    const int use_tab = (ws_size >= need_tab) ? 1 : 0;
    const int woff    = use_tab ? TABW : 0;
    const int table_n = use_tab ? 800000 : 0;
    const int prep_threads = table_n + 2944;
    const int prep_blocks  = (prep_threads + 255) / 256;

    prep<<<prep_blocks, 256, 0, stream>>>(
        (const float*)d_in[4],
        (const float*)d_in[5],  (const float*)d_in[6],
        (const float*)d_in[7],  (const float*)d_in[8],
        (const float*)d_in[9],  (const float*)d_in[10],
        (const float*)d_in[11], (const float*)d_in[12],
        (const float*)d_in[13],
        ws, table_n, woff);

    uv_agg<<<Bn, 256, 0, stream>>>(
        (const int*)d_in[0],
        (const int*)d_in[1],
        (const float*)d_in[2],
        (const float*)d_in[3],
        (const float*)d_in[4],
        (const float*)d_in[14],
        ws, woff, use_tab,
        (float*)d_out);
}

// Round 4
// 86.460 us; speedup vs baseline: 25.7246x; 2.0104x over previous
//
#include <hip/hip_runtime.h>
#include <hip/hip_bf16.h>
#include <math.h>

#define Bn 4096
#define Hn 200

typedef float f32x16 __attribute__((ext_vector_type(16)));
typedef short short8 __attribute__((ext_vector_type(8)));
typedef __bf16 bh8 __attribute__((ext_vector_type(8)));
typedef unsigned int u32;

// ---- d_ws layout (u32 units) ----
#define TABW     3200000
#define BIAS_OFF 10240
#define WR_OFF   10496
#define AT3_OFF  10560
#define WTOT     10624

union Frag { u32 w[4]; short8 s; };

__device__ __forceinline__ u32 pk2(float a, float b){
    union { __hip_bfloat162 bf; u32 u; } cv;
    cv.bf = __float22bfloat162_rn(make_float2(a, b));   // low 16 bits = first k
    return cv.u;
}

template <typename T>
__device__ __forceinline__ auto mfma_sel(T a, T b, f32x16 c, int)
    -> decltype(__builtin_amdgcn_mfma_f32_32x32x16_bf16(a, b, c, 0, 0, 0)) {
    return __builtin_amdgcn_mfma_f32_32x32x16_bf16(a, b, c, 0, 0, 0);
}
template <typename T>
__device__ __forceinline__ f32x16 mfma_sel(T a, T b, f32x16 c, long) {
    return __builtin_amdgcn_mfma_f32_32x32x16_bf16(
        __builtin_bit_cast(bh8, a), __builtin_bit_cast(bh8, b), c, 0, 0, 0);
}

__device__ __forceinline__ f32x16 mfma16v(uint4 a, const u32* b, f32x16 c){
    Frag fa, fb;
    fa.w[0] = a.x; fa.w[1] = a.y; fa.w[2] = a.z; fa.w[3] = a.w;
#pragma unroll
    for (int i = 0; i < 4; ++i) fb.w[i] = b[i];
    return mfma_sel(fa.s, fb.s, c, 0);
}
__device__ __forceinline__ f32x16 mfma16w(uint4 a, uint4 b, f32x16 c){
    Frag fa, fb;
    fa.w[0] = a.x; fa.w[1] = a.y; fa.w[2] = a.z; fa.w[3] = a.w;
    fb.w[0] = b.x; fb.w[1] = b.y; fb.w[2] = b.z; fb.w[3] = b.w;
    return mfma_sel(fa.s, fb.s, c, 0);
}

// D-tile (col=lane&31, row=(reg&3)+8*(reg>>2)+4*(lane>>5)) -> next-layer B frags
__device__ __forceinline__ void dtile_to_b(f32x16 d, u32 ow[2][4]){
    u32 p0 = pk2(d[0], d[1]),   p1 = pk2(d[2], d[3]);
    u32 p2 = pk2(d[4], d[5]),   p3 = pk2(d[6], d[7]);
    u32 p4 = pk2(d[8], d[9]),   p5 = pk2(d[10], d[11]);
    u32 p6 = pk2(d[12], d[13]), p7 = pk2(d[14], d[15]);
    auto r0 = __builtin_amdgcn_permlane32_swap(p0, p2, false, false);
    ow[0][0] = (u32)r0[0]; ow[0][2] = (u32)r0[1];
    auto r1 = __builtin_amdgcn_permlane32_swap(p1, p3, false, false);
    ow[0][1] = (u32)r1[0]; ow[0][3] = (u32)r1[1];
    auto r2 = __builtin_amdgcn_permlane32_swap(p4, p6, false, false);
    ow[1][0] = (u32)r2[0]; ow[1][2] = (u32)r2[1];
    auto r3 = __builtin_amdgcn_permlane32_swap(p5, p7, false, false);
    ow[1][1] = (u32)r3[0]; ow[1][3] = (u32)r3[1];
}

__device__ __forceinline__ void load_f16(const float* p, float bf[16]){
    const float4* q = (const float4*)p;
    float4 a = q[0], b = q[1], c = q[2], d = q[3];
    bf[0]=a.x; bf[1]=a.y; bf[2]=a.z; bf[3]=a.w;
    bf[4]=b.x; bf[5]=b.y; bf[6]=b.z; bf[7]=b.w;
    bf[8]=c.x; bf[9]=c.y; bf[10]=c.z; bf[11]=c.w;
    bf[12]=d.x; bf[13]=d.y; bf[14]=d.z; bf[15]=d.w;
}

// ======================= prep: pack weights (+ bf16 table) =======================
__global__ __launch_bounds__(256) void prep(
    const float* __restrict__ v2e_w,
    const float* __restrict__ w_r1_w, const float* __restrict__ w_r1_b,
    const float* __restrict__ w_r2_w, const float* __restrict__ w_r2_b,
    const float* __restrict__ att1_w, const float* __restrict__ att1_b,
    const float* __restrict__ att2_w, const float* __restrict__ att2_b,
    const float* __restrict__ att3_w,
    u32* __restrict__ ws, int table_n, int woff)
{
    const int g = blockIdx.x * 256 + threadIdx.x;
    if (g < table_n) {
        const float4* src = (const float4*)v2e_w + (size_t)g * 2;
        float4 a = src[0], b = src[1];
        uint4 o; o.x = pk2(a.x, a.y); o.y = pk2(a.z, a.w);
                 o.z = pk2(b.x, b.y); o.w = pk2(b.z, b.w);
        ((uint4*)ws)[g] = o;
        return;
    }
    int q = g - table_n;
    u32* wbase = ws + woff;
    if (q < 2560) {
        const int c = q >> 6, l = q & 63, lo = l & 31, h = l >> 5;
        const float* W; int ldw, ft, kc, colb;
        if (c < 8)       { W = w_r1_w; ldw = 65;  ft = c >> 2;       kc = c & 3;       colb = 0; }
        else if (c < 16) { W = w_r2_w; ldw = 64;  ft = (c - 8) >> 2; kc = (c - 8) & 3; colb = 0; }
        else if (c < 32) { int c3 = c - 16; W = att1_w; ldw = 128; ft = c3 >> 3; kc = c3 & 3; colb = 64 * ((c3 >> 2) & 1); }
        else             { int c4 = c - 32; W = att2_w; ldw = 64;  ft = c4 >> 2; kc = c4 & 3; colb = 0; }
        const float* p = W + (32 * ft + lo) * ldw + colb + 16 * kc + 8 * h;
        uint4 o; o.x = pk2(p[0], p[1]); o.y = pk2(p[2], p[3]);
                 o.z = pk2(p[4], p[5]); o.w = pk2(p[6], p[7]);
        ((uint4*)wbase)[c * 64 + l] = o;
        return;
    }
    q -= 2560;
    if (q < 256) {
        const int layer = q >> 6, ft = (q >> 5) & 1, h = (q >> 4) & 1, rg = q & 15;
        const float* bp = layer == 0 ? w_r1_b : layer == 1 ? w_r2_b : layer == 2 ? att1_b : att2_b;
        ((float*)wbase)[BIAS_OFF + q] = bp[32 * ft + (rg & 3) + 8 * (rg >> 2) + 4 * h];
        return;
    }
    q -= 256;
    if (q < 64) {
        const int ft = (q >> 5) & 1, h = (q >> 4) & 1, rg = q & 15;
        ((float*)wbase)[WR_OFF + q] = w_r1_w[(32 * ft + (rg & 3) + 8 * (rg >> 2) + 4 * h) * 65 + 64];
        return;
    }
    q -= 64;
    if (q < 64) {
        const int ft = (q >> 5) & 1, h = (q >> 4) & 1, rg = q & 15;
        ((float*)wbase)[AT3_OFF + q] = att3_w[32 * ft + (rg & 3) + 8 * (rg >> 2) + 4 * h];
    }
}

// ======================= main =======================
template<int USE_TAB>
__global__ __launch_bounds__(256, 3) void uv_agg(
    const int* __restrict__ nodes,
    const int* __restrict__ history_uv,
    const float* __restrict__ history_r,
    const float* __restrict__ u2e_w,
    const float* __restrict__ v2e_w,
    const float* __restrict__ att3_b,
    const u32* __restrict__ ws,
    float* __restrict__ out)
{
    const int b  = blockIdx.x;
    const int t  = threadIdx.x;
    const int w  = t >> 6;
    const int l  = t & 63;
    const int lo = l & 31;
    const int h  = l >> 5;

    constexpr int woff = USE_TAB ? TABW : 0;
    const uint4* WF = (const uint4*)(ws + woff);
    const float* F  = (const float*)(ws + woff);

    __shared__ u32   oh_lds[Hn * 32];    // 25.6 KB: bf16x2 words, col c at (c ^ (m&31))
    __shared__ float att_red[256];       // att, then (after barrier) per-wave reduction
    __shared__ float swax[4], ssum[4];
    __shared__ u32   u_lds[32];          // u_rep bf16-packed, word j = pk2(u[2j],u[2j+1])

    // ---- stage u_rep to LDS (block-uniform row)
    if (t < 32) {
        const int node = nodes[b];
        const float2 uv = ((const float2*)(u2e_w + (size_t)node * 64))[t];
        u_lds[t] = pk2(uv.x, uv.y);
    }

    // ---- gather indices
    const int hb  = b * Hn;
    const int m0  = 64 * w + lo;
    const int m1  = m0 + 32;
    const int mi0 = m0 < Hn ? m0 : Hn - 1;
    const int mi1 = m1 < Hn ? m1 : Hn - 1;
    const int vidx0 = history_uv[hb + mi0];
    const int vidx1 = history_uv[hb + mi1];
    const float r0  = history_r[hb + mi0];
    const float r1  = history_r[hb + mi1];

    // ---- e_uv B-fragments (both row-tiles)
    u32 eB[2][4][4];
    if constexpr (USE_TAB) {
        const uint4* t0 = (const uint4*)ws + (size_t)vidx0 * 8;
        const uint4* t1 = (const uint4*)ws + (size_t)vidx1 * 8;
#pragma unroll
        for (int kc = 0; kc < 4; ++kc){
            uint4 x = t0[2 * kc + h];
            eB[0][kc][0] = x.x; eB[0][kc][1] = x.y; eB[0][kc][2] = x.z; eB[0][kc][3] = x.w;
            uint4 y = t1[2 * kc + h];
            eB[1][kc][0] = y.x; eB[1][kc][1] = y.y; eB[1][kc][2] = y.z; eB[1][kc][3] = y.w;
        }
    } else {
        const float4* p0 = (const float4*)(v2e_w + (size_t)vidx0 * 64);
        const float4* p1 = (const float4*)(v2e_w + (size_t)vidx1 * 64);
#pragma unroll
        for (int kc = 0; kc < 4; ++kc){
            float4 a = p0[4*kc + 2*h], c = p0[4*kc + 2*h + 1];
            eB[0][kc][0] = pk2(a.x, a.y); eB[0][kc][1] = pk2(a.z, a.w);
            eB[0][kc][2] = pk2(c.x, c.y); eB[0][kc][3] = pk2(c.z, c.w);
            a = p1[4*kc + 2*h]; c = p1[4*kc + 2*h + 1];
            eB[1][kc][0] = pk2(a.x, a.y); eB[1][kc][1] = pk2(a.z, a.w);
            eB[1][kc][2] = pk2(c.x, c.y); eB[1][kc][3] = pk2(c.z, c.w);
        }
    }

    // ---- layer 1: x1 = relu(W1[:,:64] @ e + w1r*r + b1)  (transpose per tile)
    u32 x1B[2][4][4];
#pragma unroll
    for (int ft = 0; ft < 2; ++ft){
        uint4 W[4];
#pragma unroll
        for (int kc = 0; kc < 4; ++kc) W[kc] = WF[(ft*4 + kc)*64 + l];
        float bf[16], wr[16];
        load_f16(F + BIAS_OFF + ft*32 + h*16, bf);
        load_f16(F + WR_OFF  + ft*32 + h*16, wr);
#pragma unroll
        for (int rt = 0; rt < 2; ++rt){
            const float rv = rt ? r1 : r0;
            f32x16 a;
#pragma unroll
            for (int rg = 0; rg < 16; ++rg) a[rg] = fmaf(wr[rg], rv, bf[rg]);
#pragma unroll
            for (int kc = 0; kc < 4; ++kc) a = mfma16v(W[kc], eB[rt][kc], a);
#pragma unroll
            for (int i2 = 0; i2 < 16; ++i2) a[i2] = fmaxf(a[i2], 0.f);
            u32 ow[2][4];
            dtile_to_b(a, ow);
#pragma unroll
            for (int v = 0; v < 4; ++v){ x1B[rt][2*ft][v] = ow[0][v]; x1B[rt][2*ft+1][v] = ow[1][v]; }
        }
    }

    // ---- layer 2: o_history = relu(W2 @ x1 + b2)
    u32 ohB[2][4][4];
#pragma unroll
    for (int ft = 0; ft < 2; ++ft){
        uint4 W[4];
#pragma unroll
        for (int kc = 0; kc < 4; ++kc) W[kc] = WF[(8 + ft*4 + kc)*64 + l];
        float bf[16];
        load_f16(F + BIAS_OFF + 64 + ft*32 + h*16, bf);
#pragma unroll
        for (int rt = 0; rt < 2; ++rt){
            f32x16 a;
#pragma unroll
            for (int rg = 0; rg < 16; ++rg) a[rg] = bf[rg];
#pragma unroll
            for (int kc = 0; kc < 4; ++kc) a = mfma16v(W[kc], x1B[rt][kc], a);
#pragma unroll
            for (int i2 = 0; i2 < 16; ++i2) a[i2] = fmaxf(a[i2], 0.f);
            u32 ow[2][4];
            dtile_to_b(a, ow);
#pragma unroll
            for (int v = 0; v < 4; ++v){ ohB[rt][2*ft][v] = ow[0][v]; ohB[rt][2*ft+1][v] = ow[1][v]; }
        }
    }

    // stash o_history to LDS (swizzled), only real rows
#pragma unroll
    for (int kc = 0; kc < 4; ++kc)
#pragma unroll
        for (int rt = 0; rt < 2; ++rt)
#pragma unroll
            for (int v = 0; v < 4; ++v){
                const int c = 8 * kc + 4 * h + v;
                const int m = 64 * w + 32 * rt + lo;
                if (m < Hn) oh_lds[m * 32 + (c ^ lo)] = ohB[rt][kc][v];
            }

    __syncthreads();   // u_lds ready (and covers oh stash ordering later)

    // ---- layer 3: a1 = relu(A1 @ [oh ; u] + b)  K=128
    u32 a1B[2][4][4];
#pragma unroll
    for (int ft = 0; ft < 2; ++ft){
        uint4 W[4], W2[4];
#pragma unroll
        for (int kc = 0; kc < 4; ++kc) W[kc]  = WF[(16 + ft*8 + kc)*64 + l];
#pragma unroll
        for (int kc = 0; kc < 4; ++kc) W2[kc] = WF[(16 + ft*8 + 4 + kc)*64 + l];
        float bf[16];
        load_f16(F + BIAS_OFF + 128 + ft*32 + h*16, bf);
#pragma unroll
        for (int rt = 0; rt < 2; ++rt){
            f32x16 a;
#pragma unroll
            for (int rg = 0; rg < 16; ++rg) a[rg] = bf[rg];
#pragma unroll
            for (int kc = 0; kc < 4; ++kc) a = mfma16v(W[kc], ohB[rt][kc], a);
#pragma unroll
            for (int kc = 0; kc < 4; ++kc){
                const int j = 8 * kc + 4 * h;
                uint4 uu = make_uint4(u_lds[j], u_lds[j+1], u_lds[j+2], u_lds[j+3]);
                a = mfma16w(W2[kc], uu, a);
            }
#pragma unroll
            for (int i2 = 0; i2 < 16; ++i2) a[i2] = fmaxf(a[i2], 0.f);
            u32 ow[2][4];
            dtile_to_b(a, ow);
#pragma unroll
            for (int v = 0; v < 4; ++v){ a1B[rt][2*ft][v] = ow[0][v]; a1B[rt][2*ft+1][v] = ow[1][v]; }
        }
    }

    // ---- layer 4 + logit dot (acc dies per tile)
    float lgp0 = 0.f, lgp1 = 0.f;
#pragma unroll
    for (int ft = 0; ft < 2; ++ft){
        uint4 W[4];
#pragma unroll
        for (int kc = 0; kc < 4; ++kc) W[kc] = WF[(32 + ft*4 + kc)*64 + l];
        float bf[16], a3[16];
        load_f16(F + BIAS_OFF + 192 + ft*32 + h*16, bf);
        load_f16(F + AT3_OFF + ft*32 + h*16, a3);
#pragma unroll
        for (int rt = 0; rt < 2; ++rt){
            f32x16 a;
#pragma unroll
            for (int rg = 0; rg < 16; ++rg) a[rg] = bf[rg];
#pragma unroll
            for (int kc = 0; kc < 4; ++kc) a = mfma16v(W[kc], a1B[rt][kc], a);
            float p = 0.f;
#pragma unroll
            for (int rg = 0; rg < 16; ++rg) p = fmaf(fmaxf(a[rg], 0.f), a3[rg], p);
            if (rt) lgp1 += p; else lgp0 += p;
        }
    }
    const float b3 = att3_b[0];
    float lg0 = lgp0 + __shfl_xor(lgp0, 32, 64) + b3;
    float lg1 = lgp1 + __shfl_xor(lgp1, 32, 64) + b3;
    if (m0 >= Hn) lg0 = -1e30f;
    if (m1 >= Hn) lg1 = -1e30f;

    // ---- softmax over 200 rows
    float mx = fmaxf(lg0, lg1);
#pragma unroll
    for (int d = 16; d >= 1; d >>= 1) mx = fmaxf(mx, __shfl_xor(mx, d, 64));
    if (l == 0) swax[w] = mx;
    __syncthreads();
    mx = fmaxf(fmaxf(swax[0], swax[1]), fmaxf(swax[2], swax[3]));
    const float e0 = exp2f((lg0 - mx) * 1.4426950408889634f);
    const float e1 = exp2f((lg1 - mx) * 1.4426950408889634f);
    float sm = e0 + e1;
#pragma unroll
    for (int d = 16; d >= 1; d >>= 1) sm += __shfl_xor(sm, d, 64);
    if (l == 0) ssum[w] = sm;
    __syncthreads();
    const float inv = 1.f / (ssum[0] + ssum[1] + ssum[2] + ssum[3]);
    att_red[64 * w + 32 * h + lo] = (h ? e1 : e0) * inv;
    __syncthreads();

    // ---- weighted sum: out[d] = sum_m att[m] * oh[m][d]
    float s0 = 0.f, s1 = 0.f;
#pragma unroll 8
    for (int i = 0; i < 32; ++i){
        const int m  = 64 * w + 32 * h + i;
        const int mi = m < Hn ? m : Hn - 1;
        const u32 wv = oh_lds[mi * 32 + (lo ^ (mi & 31))];
        const float av = att_red[m];                      // 0 for pad rows
        s0 = fmaf(__uint_as_float(wv << 16), av, s0);
        s1 = fmaf(__uint_as_float(wv & 0xffff0000u), av, s1);
    }
    s0 += __shfl_xor(s0, 32, 64);
    s1 += __shfl_xor(s1, 32, 64);
    __syncthreads();                                      // att reads done before overlay
    if (l < 32){ att_red[w * 64 + 2 * lo] = s0; att_red[w * 64 + 2 * lo + 1] = s1; }
    __syncthreads();
    if (t < 64)
        out[b * 64 + t] = att_red[t] + att_red[64 + t] + att_red[128 + t] + att_red[192 + t];
}

extern "C" void kernel_launch(void* const* d_in, const int* in_sizes, int n_in,
                              void* d_out, int out_size, void* d_ws, size_t ws_size,
                              hipStream_t stream) {
    u32* ws = (u32*)d_ws;
    const size_t need_tab = (size_t)(TABW + WTOT) * 4;
    const int use_tab = (ws_size >= need_tab) ? 1 : 0;
    const int woff    = use_tab ? TABW : 0;
    const int table_n = use_tab ? 800000 : 0;
    const int prep_threads = table_n + 2944;
    const int prep_blocks  = (prep_threads + 255) / 256;

    prep<<<prep_blocks, 256, 0, stream>>>(
        (const float*)d_in[4],
        (const float*)d_in[5],  (const float*)d_in[6],
        (const float*)d_in[7],  (const float*)d_in[8],
        (const float*)d_in[9],  (const float*)d_in[10],
        (const float*)d_in[11], (const float*)d_in[12],
        (const float*)d_in[13],
        ws, table_n, woff);

    if (use_tab) {
        uv_agg<1><<<Bn, 256, 0, stream>>>(
            (const int*)d_in[0], (const int*)d_in[1], (const float*)d_in[2],
            (const float*)d_in[3], (const float*)d_in[4], (const float*)d_in[14],
            ws, (float*)d_out);
    } else {
        uv_agg<0><<<Bn, 256, 0, stream>>>(
            (const int*)d_in[0], (const int*)d_in[1], (const float*)d_in[2],
            (const float*)d_in[3], (const float*)d_in[4], (const float*)d_in[14],
            ws, (float*)d_out);
    }
}